// Round 14
// baseline (1394.856 us; speedup 1.0000x reference)
//
#include <hip/hip_runtime.h>
#include <hip/hip_fp16.h>
#include <cmath>

#define N_NODES 100000
#define N_EDGES 3200000
#define ALPHA   0.1f
#define ITERS   10
#define NBUK    1024
#define RPB     98      // rows per bucket; NBUK*RPB = 100352 >= N_NODES
#define CHUNK   8192
#define NCH     391     // ceil(N_EDGES / CHUNK)
#define PLANE   ((size_t)N_NODES * 16)   // halfs per 16-label plane

typedef __attribute__((ext_vector_type(8))) short short8;
typedef __attribute__((ext_vector_type(4))) float f32x4;

__device__ __forceinline__ short f2bf(float x) {
    union { float f; unsigned u; } v; v.f = x;
    unsigned r = v.u + 0x7fffu + ((v.u >> 16) & 1u);   // RNE
    return (short)(r >> 16);
}

// ---------------------------------------------------------------------------
// One-time weight prep: W1[512][64] -> W1t[64][512] bf16 ; W2 -> W2t bf16
// ---------------------------------------------------------------------------
__global__ void prep_w(const float* __restrict__ W1, const float* __restrict__ W2,
                       short* __restrict__ W1t, short* __restrict__ W2t)
{
    int t = blockIdx.x * 256 + threadIdx.x;
    if (t < 512 * 64) { int k = t >> 6, c = t & 63; W1t[c * 512 + k] = f2bf(W1[t]); }
    if (t < 64 * 64)  { int k = t >> 6, c = t & 63; W2t[c * 64 + k]  = f2bf(W2[t]); }
}

// ---------------------------------------------------------------------------
// Fused MFMA MLP (r12 structure): q0 = fp16( relu(F@W1+b1)@W2+b2 ),
// stored PLANE-MAJOR: q0[g][node][16] for 16-label group g = col/16.
// ---------------------------------------------------------------------------
__global__ __launch_bounds__(128) void mlp_mfma(
    const float* __restrict__ F, const short* __restrict__ W1t,
    const short* __restrict__ W2t, const float* __restrict__ b1,
    const float* __restrict__ b2, __half* __restrict__ q0)
{
    __shared__ short Ft[32 * 128];
    __shared__ short Ht[32 * 64];

    const int t  = threadIdx.x;
    const int l  = t & 63;
    const int wv = t >> 6;
    const int wr = wv * 16;
    const long base = (long)blockIdx.x * 32;

    const int sr = t >> 2;
    const int ck = (t & 3) * 32;

    float4 f0, f1, f2, f3, f4, f5, f6, f7;

#define LOAD_TILE(kt) do {                                                   \
    const float* p_ = F + (base + sr) * 512 + (kt) * 128 + ck;               \
    f0 = *(const float4*)(p_ +  0);  f1 = *(const float4*)(p_ +  4);         \
    f2 = *(const float4*)(p_ +  8);  f3 = *(const float4*)(p_ + 12);         \
    f4 = *(const float4*)(p_ + 16);  f5 = *(const float4*)(p_ + 20);         \
    f6 = *(const float4*)(p_ + 24);  f7 = *(const float4*)(p_ + 28);         \
} while (0)

#define STORE_PAIR(j2, fa, fb) do {                                          \
    int k_ = ck + (j2) * 8;                                                  \
    short8 s_ = { f2bf((fa).x), f2bf((fa).y), f2bf((fa).z), f2bf((fa).w),    \
                  f2bf((fb).x), f2bf((fb).y), f2bf((fb).z), f2bf((fb).w) };  \
    *(short8*)&Ft[(sr * 128 + k_) ^ ((sr & 7) << 3)] = s_;                   \
} while (0)

    LOAD_TILE(0);

    f32x4 acc[4] = {};
    for (int kt = 0; kt < 4; ++kt) {
        STORE_PAIR(0, f0, f1);
        STORE_PAIR(1, f2, f3);
        STORE_PAIR(2, f4, f5);
        STORE_PAIR(3, f6, f7);
        __syncthreads();
        if (kt < 3) LOAD_TILE(kt + 1);
#pragma unroll
        for (int kc = 0; kc < 4; ++kc) {
            int kb = kc * 32 + (l >> 4) * 8;
            int ar = wr + (l & 15);
            short8 a = *(const short8*)&Ft[(ar * 128 + kb) ^ ((ar & 7) << 3)];
#pragma unroll
            for (int n = 0; n < 4; ++n) {
                int bc = n * 16 + (l & 15);
                short8 b = *(const short8*)(W1t + bc * 512 + kt * 128 + kb);
                acc[n] = __builtin_amdgcn_mfma_f32_16x16x32_bf16(a, b, acc[n], 0, 0, 0);
            }
        }
        __syncthreads();
    }

#pragma unroll
    for (int n = 0; n < 4; ++n) {
        int col = n * 16 + (l & 15);
        float bv = b1[col];
#pragma unroll
        for (int i = 0; i < 4; ++i) {
            int row = wr + (l >> 4) * 4 + i;
            float hv = fmaxf(acc[n][i] + bv, 0.0f);
            Ht[(row * 64 + col) ^ ((row & 7) << 3)] = f2bf(hv);
        }
    }
    f32x4 acc2[4] = {};
#pragma unroll
    for (int kc = 0; kc < 2; ++kc) {
        int kb = kc * 32 + (l >> 4) * 8;
        int ar = wr + (l & 15);
        short8 a = *(const short8*)&Ht[(ar * 64 + kb) ^ ((ar & 7) << 3)];
#pragma unroll
        for (int n = 0; n < 4; ++n) {
            int bc = n * 16 + (l & 15);
            short8 b = *(const short8*)(W2t + bc * 64 + kb);
            acc2[n] = __builtin_amdgcn_mfma_f32_16x16x32_bf16(a, b, acc2[n], 0, 0, 0);
        }
    }
#pragma unroll
    for (int n = 0; n < 4; ++n) {
        float bv = b2[n * 16 + (l & 15)];
#pragma unroll
        for (int i = 0; i < 4; ++i) {
            long row = base + wr + (l >> 4) * 4 + i;
            // plane-major: plane n, node row, label (l&15)
            q0[(size_t)n * PLANE + row * 16 + (l & 15)] = __float2half(acc2[n][i] + bv);
        }
    }
#undef LOAD_TILE
#undef STORE_PAIR
}

// ---------------------------------------------------------------------------
// Radix-partition by bucket (no global atomics)
// ---------------------------------------------------------------------------
__global__ __launch_bounds__(256) void bhist(const int* __restrict__ rows, int* __restrict__ gh)
{
    __shared__ int cnt[NBUK];
    for (int i = threadIdx.x; i < NBUK; i += 256) cnt[i] = 0;
    __syncthreads();
    int base = blockIdx.x * CHUNK;
    int end  = base + CHUNK; if (end > N_EDGES) end = N_EDGES;
    for (int i = base + threadIdx.x; i < end; i += 256)
        atomicAdd(&cnt[rows[i] / RPB], 1);
    __syncthreads();
    for (int i = threadIdx.x; i < NBUK; i += 256)
        gh[i * NCH + blockIdx.x] = cnt[i];
}

__global__ __launch_bounds__(512) void bscan(int* __restrict__ gh, int* __restrict__ btot)
{
    __shared__ int s[512];
    int k = blockIdx.x;
    int t = threadIdx.x;
    int v = (t < NCH) ? gh[k * NCH + t] : 0;
    s[t] = v;
    __syncthreads();
    for (int off = 1; off < 512; off <<= 1) {
        int x = (t >= off) ? s[t - off] : 0;
        __syncthreads();
        s[t] += x;
        __syncthreads();
    }
    if (t < NCH) gh[k * NCH + t] = s[t] - v;
    if (t == NCH - 1) btot[k] = s[t];
}

__global__ __launch_bounds__(1024) void scan_btot(const int* __restrict__ btot, int* __restrict__ bbase)
{
    __shared__ int s[1024];
    int t = threadIdx.x;
    int v = btot[t];
    s[t] = v;
    __syncthreads();
    for (int off = 1; off < 1024; off <<= 1) {
        int x = (t >= off) ? s[t - off] : 0;
        __syncthreads();
        s[t] += x;
        __syncthreads();
    }
    bbase[t] = s[t] - v;
}

__global__ __launch_bounds__(256) void bpart(const int* __restrict__ rows, const int* __restrict__ cols,
                                             const float* __restrict__ w, const int* __restrict__ gh,
                                             const int* __restrict__ bbase, uint2* __restrict__ stg)
{
    __shared__ int cur[NBUK];
    int blk = blockIdx.x;
    for (int i = threadIdx.x; i < NBUK; i += 256)
        cur[i] = bbase[i] + gh[i * NCH + blk];
    __syncthreads();
    int base = blk * CHUNK;
    int end  = base + CHUNK; if (end > N_EDGES) end = N_EDGES;
    for (int i = base + threadIdx.x; i < end; i += 256) {
        int r = rows[i];
        int b = r / RPB;
        int pos = atomicAdd(&cur[b], 1);
        float ws = w[i] * ((1.0f - ALPHA) / 16.0f);
        unsigned meta = (unsigned)cols[i] | ((unsigned)(r - b * RPB) << 17);
        stg[pos] = make_uint2(meta, __float_as_uint(ws));
    }
}

// one block per bucket: row-degree count, scan, emit rowp, scatter packed 4B cw
__global__ __launch_bounds__(256) void bucket_sort2(const int* __restrict__ bbase,
                                                    const uint2* __restrict__ stg,
                                                    unsigned* __restrict__ cw,
                                                    int* __restrict__ rowp)
{
    __shared__ int ldeg[RPB];
    __shared__ int lcur[RPB];
    __shared__ int sc[128];
    const int b = blockIdx.x;
    const int rowlo = b * RPB;
    if (rowlo >= N_NODES) return;
    int rowhi = rowlo + RPB; if (rowhi > N_NODES) rowhi = N_NODES;
    const int nrows = rowhi - rowlo;
    const int t = threadIdx.x;
    const int base = bbase[b];
    const int cnt = ((b + 1 < NBUK) ? bbase[b + 1] : N_EDGES) - base;

    if (t < RPB) ldeg[t] = 0;
    __syncthreads();
    for (int j = t; j < cnt; j += 256)
        atomicAdd(&ldeg[stg[base + j].x >> 17], 1);
    __syncthreads();
    int v = 0;
    if (t < 128) { v = (t < nrows) ? ldeg[t] : 0; sc[t] = v; }
    __syncthreads();
    for (int off = 1; off < 128; off <<= 1) {
        int x = (t < 128 && t >= off) ? sc[t - off] : 0;
        __syncthreads();
        if (t < 128) sc[t] += x;
        __syncthreads();
    }
    if (t < nrows) {
        int rp = base + sc[t] - v;
        rowp[rowlo + t] = rp;
        lcur[t] = rp;
    }
    if (t == 0 && rowhi == N_NODES) rowp[N_NODES] = base + cnt;
    __syncthreads();
    for (int j = t; j < cnt; j += 256) {
        uint2 rec = stg[base + j];
        int roff = rec.x >> 17;
        unsigned col = rec.x & 0x1FFFFu;
        int pos = atomicAdd(&lcur[roff], 1);
        unsigned short hb = __half_as_ushort(__float2half(__uint_as_float(rec.y)));
        cw[pos] = col | ((unsigned)hb << 17);
    }
}

// ---------------------------------------------------------------------------
// SpMM, label-plane phased: block group g handles plane g (16 labels, 3.2MB
// contiguous — fits an XCD L2). Blocks ordered group-major so co-resident
// blocks share the plane. One wave per row; 16 edge-slots x 4 lanes x 8B.
// ---------------------------------------------------------------------------
template <int LAST>
__global__ __launch_bounds__(256) void spmm_kernel(
    const int* __restrict__ rowp, const unsigned* __restrict__ cw,
    const __half* __restrict__ qin, const __half* __restrict__ zh,
    float beta, float outscale,
    __half* __restrict__ qout, float* __restrict__ out)
{
    const int g   = blockIdx.x / 25000;             // label group 0..3
    const int wid = (blockIdx.x % 25000) * 4 + (threadIdx.x >> 6);
    const int lane = threadIdx.x & 63;
    const int slot = lane >> 2;   // 0..15 edge sub-slot
    const int l4   = lane & 3;    // 8B chunk (4 labels)

    const __half* qg = qin + (size_t)g * PLANE;

    const int start = rowp[wid];
    const int end   = rowp[wid + 1];

    // hoisted teleport term (plane g, row wid)
    uint2 zv = *(const uint2*)(zh + (size_t)g * PLANE + wid * 16 + l4 * 4);

    float a0 = 0, a1 = 0, a2 = 0, a3 = 0;

#define ACC_EDGE(pc, v)                                                       \
    do {                                                                      \
        float ww_ = __half2float(__ushort_as_half((unsigned short)((pc) >> 17))); \
        float2 p_;                                                            \
        p_ = __half22float2(*(__half2*)&(v).x); a0 += ww_ * p_.x; a1 += ww_ * p_.y; \
        p_ = __half22float2(*(__half2*)&(v).y); a2 += ww_ * p_.x; a3 += ww_ * p_.y; \
    } while (0)

    int e = start + slot;
    for (; e + 16 < end; e += 32) {
        unsigned pc0 = cw[e];
        unsigned pc1 = cw[e + 16];
        uint2 v0 = *(const uint2*)(qg + (size_t)(pc0 & 0x1FFFFu) * 16 + l4 * 4);
        uint2 v1 = *(const uint2*)(qg + (size_t)(pc1 & 0x1FFFFu) * 16 + l4 * 4);
        ACC_EDGE(pc0, v0);
        ACC_EDGE(pc1, v1);
    }
    if (e < end) {
        unsigned pc = cw[e];
        uint2 v = *(const uint2*)(qg + (size_t)(pc & 0x1FFFFu) * 16 + l4 * 4);
        ACC_EDGE(pc, v);
    }
#undef ACC_EDGE

    a0 += __shfl_xor(a0, 4);  a1 += __shfl_xor(a1, 4);
    a2 += __shfl_xor(a2, 4);  a3 += __shfl_xor(a3, 4);
    a0 += __shfl_xor(a0, 8);  a1 += __shfl_xor(a1, 8);
    a2 += __shfl_xor(a2, 8);  a3 += __shfl_xor(a3, 8);
    a0 += __shfl_xor(a0, 16); a1 += __shfl_xor(a1, 16);
    a2 += __shfl_xor(a2, 16); a3 += __shfl_xor(a3, 16);
    a0 += __shfl_xor(a0, 32); a1 += __shfl_xor(a1, 32);
    a2 += __shfl_xor(a2, 32); a3 += __shfl_xor(a3, 32);

    if (lane < 4) {
        float2 z0 = __half22float2(*(__half2*)&zv.x);
        float2 z1 = __half22float2(*(__half2*)&zv.y);
        float o0 = a0 + beta * z0.x, o1 = a1 + beta * z0.y;
        float o2 = a2 + beta * z1.x, o3 = a3 + beta * z1.y;
        if (LAST) {
            float4 r = { outscale * o0, outscale * o1, outscale * o2, outscale * o3 };
            *(float4*)(out + (size_t)wid * 64 + g * 16 + lane * 4) = r;
        } else {
            __half2 h0 = __floats2half2_rn(o0, o1);
            __half2 h1 = __floats2half2_rn(o2, o3);
            uint2 pv = { *(unsigned*)&h0, *(unsigned*)&h1 };
            *(uint2*)(qout + (size_t)g * PLANE + wid * 16 + lane * 4) = pv;
        }
    }
}

// ---------------------------------------------------------------------------
extern "C" void kernel_launch(void* const* d_in, const int* in_sizes, int n_in,
                              void* d_out, int out_size, void* d_ws, size_t ws_size,
                              hipStream_t stream)
{
    const float* features = (const float*)d_in[0];
    const float* W1 = (const float*)d_in[1];
    const float* b1 = (const float*)d_in[2];
    const float* W2 = (const float*)d_in[3];
    const float* b2 = (const float*)d_in[4];
    const float* ew = (const float*)d_in[5];
    const int*   ei = (const int*)d_in[6];
    const int* erow = ei;
    const int* ecol = ei + N_EDGES;
    float* out = (float*)d_out;

    char* ws = (char*)d_ws;
    size_t off = 0;
    auto alloc = [&](size_t bytes) {
        size_t c = off;
        off += (bytes + 255) & ~(size_t)255;
        return c;
    };
    __half* q0    = (__half*)(ws + alloc((size_t)N_NODES * 64 * 2));
    __half* qA    = (__half*)(ws + alloc((size_t)N_NODES * 64 * 2));
    __half* qB    = (__half*)(ws + alloc((size_t)N_NODES * 64 * 2));
    unsigned* cw  = (unsigned*)(ws + alloc((size_t)N_EDGES * 4));
    uint2* stg    = (uint2*)(ws + alloc((size_t)N_EDGES * 8));
    int*   gh     = (int*)  (ws + alloc((size_t)NBUK * NCH * 4));
    short* W1t    = (short*)(ws + alloc((size_t)512 * 64 * 2));
    short* W2t    = (short*)(ws + alloc((size_t)64 * 64 * 2));
    int*   rowp   = (int*)  (ws + alloc((size_t)(N_NODES + 1) * 4));
    int*   btot   = (int*)  (ws + alloc((size_t)NBUK * 4));
    int*   bbase  = (int*)  (ws + alloc((size_t)NBUK * 4));
    (void)ws_size; (void)in_sizes; (void)n_in; (void)out_size;

    // 1) weight prep + MLP head (q0 = fp16 z, plane-major, doubles as teleport)
    prep_w<<<128, 256, 0, stream>>>(W1, W2, W1t, W2t);
    mlp_mfma<<<N_NODES / 32, 128, 0, stream>>>(features, W1t, W2t, b1, b2, q0);

    // 2) CSR build: radix partition by bucket, then in-bucket row sort (+rowp)
    bhist<<<NCH, 256, 0, stream>>>(erow, gh);
    bscan<<<NBUK, 512, 0, stream>>>(gh, btot);
    scan_btot<<<1, 1024, 0, stream>>>(btot, bbase);
    bpart<<<NCH, 256, 0, stream>>>(erow, ecol, ew, gh, bbase, stg);
    bucket_sort2<<<NBUK, 256, 0, stream>>>(bbase, stg, cw, rowp);

    // 3) 10 propagation iterations on scaled fp16 state (c = 16),
    //    label-plane phased (4 groups x 25000 blocks, group-major order)
    const __half* qi = q0;
    for (int it = 1; it < ITERS; ++it) {
        __half* qo = (it & 1) ? qA : qB;
        float beta = (float)(0.1 / pow(16.0, (double)it));
        spmm_kernel<0><<<100000, 256, 0, stream>>>(rowp, cw, qi, q0, beta, 1.0f, qo, nullptr);
        qi = qo;
    }
    float beta10 = (float)(0.1 / pow(16.0, 10.0));
    float osc    = (float)pow(16.0, 10.0);
    spmm_kernel<1><<<100000, 256, 0, stream>>>(rowp, cw, qi, q0, beta10, osc, nullptr, out);
}

// Round 15
// 742.141 us; speedup vs baseline: 1.8795x; 1.8795x over previous
//
#include <hip/hip_runtime.h>
#include <hip/hip_fp16.h>
#include <cmath>

#define N_NODES 100000
#define N_EDGES 3200000
#define ALPHA   0.1f
#define ITERS   10
#define NBUK    1024
#define RPB     98      // rows per bucket; NBUK*RPB = 100352 >= N_NODES
#define CHUNK   8192
#define NCH     391     // ceil(N_EDGES / CHUNK)

typedef __attribute__((ext_vector_type(8))) short short8;
typedef __attribute__((ext_vector_type(4))) float f32x4;

__device__ __forceinline__ short f2bf(float x) {
    union { float f; unsigned u; } v; v.f = x;
    unsigned r = v.u + 0x7fffu + ((v.u >> 16) & 1u);   // RNE
    return (short)(r >> 16);
}

// ---------------------------------------------------------------------------
// One-time weight prep: W1[512][64] -> W1t[64][512] bf16 ; W2 -> W2t bf16
// ---------------------------------------------------------------------------
__global__ void prep_w(const float* __restrict__ W1, const float* __restrict__ W2,
                       short* __restrict__ W1t, short* __restrict__ W2t)
{
    int t = blockIdx.x * 256 + threadIdx.x;
    if (t < 512 * 64) { int k = t >> 6, c = t & 63; W1t[c * 512 + k] = f2bf(W1[t]); }
    if (t < 64 * 64)  { int k = t >> 6, c = t & 63; W2t[c * 64 + k]  = f2bf(W2[t]); }
}

// ---------------------------------------------------------------------------
// Fused MFMA MLP, direct-from-global A-fragments (no F staging, no barriers):
// lane l reads F[row l&15][k-slice (l>>4)*8] as 2x float4, cvt f32->bf16
// in-register. H kept wave-local in LDS (same-wave write->read, lgkmcnt only).
// q0 = fp16( relu(F @ W1 + b1) @ W2 + b2 ), row-major.
// ---------------------------------------------------------------------------
__global__ __launch_bounds__(128) void mlp_mfma(
    const float* __restrict__ F, const short* __restrict__ W1t,
    const short* __restrict__ W2t, const float* __restrict__ b1,
    const float* __restrict__ b2, __half* __restrict__ q0)
{
    __shared__ short Ht[2][16 * 64];

    const int t  = threadIdx.x;      // 0..127
    const int l  = t & 63;
    const int wv = t >> 6;           // wave 0..1
    short* ht = Ht[wv];
    const long base = (long)blockIdx.x * 32 + wv * 16;   // wave's 16 rows

    const int ar = l & 15;           // A-fragment row within tile
    const int kg = (l >> 4) * 8;     // k offset within 32-wide kc block
    const float* frow = F + (base + ar) * 512;

    f32x4 acc[4] = {};
#pragma unroll
    for (int kt = 0; kt < 4; ++kt) {
#pragma unroll
        for (int kc = 0; kc < 4; ++kc) {
            const int kb = kt * 128 + kc * 32 + kg;
            float4 fa = *(const float4*)(frow + kb);
            float4 fb = *(const float4*)(frow + kb + 4);
            short8 a = { f2bf(fa.x), f2bf(fa.y), f2bf(fa.z), f2bf(fa.w),
                         f2bf(fb.x), f2bf(fb.y), f2bf(fb.z), f2bf(fb.w) };
#pragma unroll
            for (int n = 0; n < 4; ++n) {
                int bc = n * 16 + (l & 15);
                short8 b = *(const short8*)(W1t + bc * 512 + kb);
                acc[n] = __builtin_amdgcn_mfma_f32_16x16x32_bf16(a, b, acc[n], 0, 0, 0);
            }
        }
    }

    // relu + bias -> wave-local Ht (no barrier: same-wave LDS dependency)
#pragma unroll
    for (int n = 0; n < 4; ++n) {
        int col = n * 16 + (l & 15);
        float bv = b1[col];
#pragma unroll
        for (int i = 0; i < 4; ++i) {
            int row = (l >> 4) * 4 + i;
            float hv = fmaxf(acc[n][i] + bv, 0.0f);
            ht[(row * 64 + col) ^ ((row & 7) << 3)] = f2bf(hv);
        }
    }
    f32x4 acc2[4] = {};
#pragma unroll
    for (int kc = 0; kc < 2; ++kc) {
        int kb = kc * 32 + kg;
        short8 a = *(const short8*)&ht[(ar * 64 + kb) ^ ((ar & 7) << 3)];
#pragma unroll
        for (int n = 0; n < 4; ++n) {
            int bc = n * 16 + (l & 15);
            short8 b = *(const short8*)(W2t + bc * 64 + kb);
            acc2[n] = __builtin_amdgcn_mfma_f32_16x16x32_bf16(a, b, acc2[n], 0, 0, 0);
        }
    }
#pragma unroll
    for (int n = 0; n < 4; ++n) {
        int col = n * 16 + (l & 15);
        float bv = b2[col];
#pragma unroll
        for (int i = 0; i < 4; ++i) {
            long row = base + (l >> 4) * 4 + i;
            q0[row * 64 + col] = __float2half(acc2[n][i] + bv);
        }
    }
}

// ---------------------------------------------------------------------------
// Radix-partition by bucket (no global atomics)
// ---------------------------------------------------------------------------
__global__ __launch_bounds__(256) void bhist(const int* __restrict__ rows, int* __restrict__ gh)
{
    __shared__ int cnt[NBUK];
    for (int i = threadIdx.x; i < NBUK; i += 256) cnt[i] = 0;
    __syncthreads();
    int base = blockIdx.x * CHUNK;
    int end  = base + CHUNK; if (end > N_EDGES) end = N_EDGES;
    for (int i = base + threadIdx.x; i < end; i += 256)
        atomicAdd(&cnt[rows[i] / RPB], 1);
    __syncthreads();
    for (int i = threadIdx.x; i < NBUK; i += 256)
        gh[i * NCH + blockIdx.x] = cnt[i];
}

__global__ __launch_bounds__(512) void bscan(int* __restrict__ gh, int* __restrict__ btot)
{
    __shared__ int s[512];
    int k = blockIdx.x;
    int t = threadIdx.x;
    int v = (t < NCH) ? gh[k * NCH + t] : 0;
    s[t] = v;
    __syncthreads();
    for (int off = 1; off < 512; off <<= 1) {
        int x = (t >= off) ? s[t - off] : 0;
        __syncthreads();
        s[t] += x;
        __syncthreads();
    }
    if (t < NCH) gh[k * NCH + t] = s[t] - v;
    if (t == NCH - 1) btot[k] = s[t];
}

__global__ __launch_bounds__(1024) void scan_btot(const int* __restrict__ btot, int* __restrict__ bbase)
{
    __shared__ int s[1024];
    int t = threadIdx.x;
    int v = btot[t];
    s[t] = v;
    __syncthreads();
    for (int off = 1; off < 1024; off <<= 1) {
        int x = (t >= off) ? s[t - off] : 0;
        __syncthreads();
        s[t] += x;
        __syncthreads();
    }
    bbase[t] = s[t] - v;
}

__global__ __launch_bounds__(256) void bpart(const int* __restrict__ rows, const int* __restrict__ cols,
                                             const float* __restrict__ w, const int* __restrict__ gh,
                                             const int* __restrict__ bbase, uint2* __restrict__ stg)
{
    __shared__ int cur[NBUK];
    int blk = blockIdx.x;
    for (int i = threadIdx.x; i < NBUK; i += 256)
        cur[i] = bbase[i] + gh[i * NCH + blk];
    __syncthreads();
    int base = blk * CHUNK;
    int end  = base + CHUNK; if (end > N_EDGES) end = N_EDGES;
    for (int i = base + threadIdx.x; i < end; i += 256) {
        int r = rows[i];
        int b = r / RPB;
        int pos = atomicAdd(&cur[b], 1);
        float ws = w[i] * ((1.0f - ALPHA) / 16.0f);
        unsigned meta = (unsigned)cols[i] | ((unsigned)(r - b * RPB) << 17);
        stg[pos] = make_uint2(meta, __float_as_uint(ws));
    }
}

// one block per bucket: row-degree count, scan, emit rowp, scatter packed 4B cw
__global__ __launch_bounds__(256) void bucket_sort2(const int* __restrict__ bbase,
                                                    const uint2* __restrict__ stg,
                                                    unsigned* __restrict__ cw,
                                                    int* __restrict__ rowp)
{
    __shared__ int ldeg[RPB];
    __shared__ int lcur[RPB];
    __shared__ int sc[128];
    const int b = blockIdx.x;
    const int rowlo = b * RPB;
    if (rowlo >= N_NODES) return;
    int rowhi = rowlo + RPB; if (rowhi > N_NODES) rowhi = N_NODES;
    const int nrows = rowhi - rowlo;
    const int t = threadIdx.x;
    const int base = bbase[b];
    const int cnt = ((b + 1 < NBUK) ? bbase[b + 1] : N_EDGES) - base;

    if (t < RPB) ldeg[t] = 0;
    __syncthreads();
    for (int j = t; j < cnt; j += 256)
        atomicAdd(&ldeg[stg[base + j].x >> 17], 1);
    __syncthreads();
    int v = 0;
    if (t < 128) { v = (t < nrows) ? ldeg[t] : 0; sc[t] = v; }
    __syncthreads();
    for (int off = 1; off < 128; off <<= 1) {
        int x = (t < 128 && t >= off) ? sc[t - off] : 0;
        __syncthreads();
        if (t < 128) sc[t] += x;
        __syncthreads();
    }
    if (t < nrows) {
        int rp = base + sc[t] - v;
        rowp[rowlo + t] = rp;
        lcur[t] = rp;
    }
    if (t == 0 && rowhi == N_NODES) rowp[N_NODES] = base + cnt;
    __syncthreads();
    for (int j = t; j < cnt; j += 256) {
        uint2 rec = stg[base + j];
        int roff = rec.x >> 17;
        unsigned col = rec.x & 0x1FFFFu;
        int pos = atomicAdd(&lcur[roff], 1);
        unsigned short hb = __half_as_ushort(__float2half(__uint_as_float(rec.y)));
        cw[pos] = col | ((unsigned)hb << 17);
    }
}

// ---------------------------------------------------------------------------
// SpMM on scaled fp16 state: q_t = sum w' * q_{t-1}[col] + beta_t * zh
// r12-proven geometry: 8 sub-slots x 8 lanes x 16B gathers, unroll 2;
// cw packed 4B/edge: col 17b | fp16-weight 15b.
// ---------------------------------------------------------------------------
template <int LAST>
__global__ __launch_bounds__(256) void spmm_kernel(
    const int* __restrict__ rowp, const unsigned* __restrict__ cw,
    const __half* __restrict__ qin, const __half* __restrict__ zh,
    float beta, float outscale,
    __half* __restrict__ qout, float* __restrict__ out)
{
    const int wid = blockIdx.x * 4 + (threadIdx.x >> 6);
    if (wid >= N_NODES) return;
    const int lane = threadIdx.x & 63;
    const int sub  = lane >> 3;   // 0..7
    const int l8   = lane & 7;    // 16B chunk (8 labels)

    const int start = rowp[wid];
    const int end   = rowp[wid + 1];

    uint4 zv = *(const uint4*)(zh + (long)wid * 64 + l8 * 8);

    float a0 = 0, a1 = 0, a2 = 0, a3 = 0, a4 = 0, a5 = 0, a6 = 0, a7 = 0;

#define ACC_EDGE(pc, v)                                                       \
    do {                                                                      \
        float ww_ = __half2float(__ushort_as_half((unsigned short)((pc) >> 17))); \
        float2 p_;                                                            \
        p_ = __half22float2(*(__half2*)&(v).x); a0 += ww_ * p_.x; a1 += ww_ * p_.y; \
        p_ = __half22float2(*(__half2*)&(v).y); a2 += ww_ * p_.x; a3 += ww_ * p_.y; \
        p_ = __half22float2(*(__half2*)&(v).z); a4 += ww_ * p_.x; a5 += ww_ * p_.y; \
        p_ = __half22float2(*(__half2*)&(v).w); a6 += ww_ * p_.x; a7 += ww_ * p_.y; \
    } while (0)

    int e = start + sub;
    for (; e + 8 < end; e += 16) {
        unsigned pc0 = cw[e];
        unsigned pc1 = cw[e + 8];
        uint4 v0 = *(const uint4*)(qin + (long)(pc0 & 0x1FFFFu) * 64 + l8 * 8);
        uint4 v1 = *(const uint4*)(qin + (long)(pc1 & 0x1FFFFu) * 64 + l8 * 8);
        ACC_EDGE(pc0, v0);
        ACC_EDGE(pc1, v1);
    }
    if (e < end) {
        unsigned pc = cw[e];
        uint4 v = *(const uint4*)(qin + (long)(pc & 0x1FFFFu) * 64 + l8 * 8);
        ACC_EDGE(pc, v);
    }
#undef ACC_EDGE

    a0 += __shfl_xor(a0, 8);  a1 += __shfl_xor(a1, 8);
    a2 += __shfl_xor(a2, 8);  a3 += __shfl_xor(a3, 8);
    a4 += __shfl_xor(a4, 8);  a5 += __shfl_xor(a5, 8);
    a6 += __shfl_xor(a6, 8);  a7 += __shfl_xor(a7, 8);
    a0 += __shfl_xor(a0, 16); a1 += __shfl_xor(a1, 16);
    a2 += __shfl_xor(a2, 16); a3 += __shfl_xor(a3, 16);
    a4 += __shfl_xor(a4, 16); a5 += __shfl_xor(a5, 16);
    a6 += __shfl_xor(a6, 16); a7 += __shfl_xor(a7, 16);
    a0 += __shfl_xor(a0, 32); a1 += __shfl_xor(a1, 32);
    a2 += __shfl_xor(a2, 32); a3 += __shfl_xor(a3, 32);
    a4 += __shfl_xor(a4, 32); a5 += __shfl_xor(a5, 32);
    a6 += __shfl_xor(a6, 32); a7 += __shfl_xor(a7, 32);

    if (lane < 8) {
        float2 z0 = __half22float2(*(__half2*)&zv.x);
        float2 z1 = __half22float2(*(__half2*)&zv.y);
        float2 z2 = __half22float2(*(__half2*)&zv.z);
        float2 z3 = __half22float2(*(__half2*)&zv.w);
        float o0 = a0 + beta * z0.x, o1 = a1 + beta * z0.y;
        float o2 = a2 + beta * z1.x, o3 = a3 + beta * z1.y;
        float o4 = a4 + beta * z2.x, o5 = a5 + beta * z2.y;
        float o6 = a6 + beta * z3.x, o7 = a7 + beta * z3.y;
        if (LAST) {
            float4 ra = { outscale * o0, outscale * o1, outscale * o2, outscale * o3 };
            float4 rb = { outscale * o4, outscale * o5, outscale * o6, outscale * o7 };
            *(float4*)(out + (long)wid * 64 + lane * 8)     = ra;
            *(float4*)(out + (long)wid * 64 + lane * 8 + 4) = rb;
        } else {
            __half2 h0 = __floats2half2_rn(o0, o1);
            __half2 h1 = __floats2half2_rn(o2, o3);
            __half2 h2 = __floats2half2_rn(o4, o5);
            __half2 h3 = __floats2half2_rn(o6, o7);
            uint4 pv = { *(unsigned*)&h0, *(unsigned*)&h1, *(unsigned*)&h2, *(unsigned*)&h3 };
            *(uint4*)(qout + (long)wid * 64 + lane * 8) = pv;
        }
    }
}

// ---------------------------------------------------------------------------
extern "C" void kernel_launch(void* const* d_in, const int* in_sizes, int n_in,
                              void* d_out, int out_size, void* d_ws, size_t ws_size,
                              hipStream_t stream)
{
    const float* features = (const float*)d_in[0];
    const float* W1 = (const float*)d_in[1];
    const float* b1 = (const float*)d_in[2];
    const float* W2 = (const float*)d_in[3];
    const float* b2 = (const float*)d_in[4];
    const float* ew = (const float*)d_in[5];
    const int*   ei = (const int*)d_in[6];
    const int* erow = ei;
    const int* ecol = ei + N_EDGES;
    float* out = (float*)d_out;

    char* ws = (char*)d_ws;
    size_t off = 0;
    auto alloc = [&](size_t bytes) {
        size_t c = off;
        off += (bytes + 255) & ~(size_t)255;
        return c;
    };
    __half* q0    = (__half*)(ws + alloc((size_t)N_NODES * 64 * 2));
    __half* qA    = (__half*)(ws + alloc((size_t)N_NODES * 64 * 2));
    __half* qB    = (__half*)(ws + alloc((size_t)N_NODES * 64 * 2));
    unsigned* cw  = (unsigned*)(ws + alloc((size_t)N_EDGES * 4));
    uint2* stg    = (uint2*)(ws + alloc((size_t)N_EDGES * 8));
    int*   gh     = (int*)  (ws + alloc((size_t)NBUK * NCH * 4));
    short* W1t    = (short*)(ws + alloc((size_t)512 * 64 * 2));
    short* W2t    = (short*)(ws + alloc((size_t)64 * 64 * 2));
    int*   rowp   = (int*)  (ws + alloc((size_t)(N_NODES + 1) * 4));
    int*   btot   = (int*)  (ws + alloc((size_t)NBUK * 4));
    int*   bbase  = (int*)  (ws + alloc((size_t)NBUK * 4));
    (void)ws_size; (void)in_sizes; (void)n_in; (void)out_size;

    // 1) weight prep + MLP head (q0 = fp16 z, row-major, doubles as teleport)
    prep_w<<<128, 256, 0, stream>>>(W1, W2, W1t, W2t);
    mlp_mfma<<<N_NODES / 32, 128, 0, stream>>>(features, W1t, W2t, b1, b2, q0);

    // 2) CSR build: radix partition by bucket, then in-bucket row sort (+rowp)
    bhist<<<NCH, 256, 0, stream>>>(erow, gh);
    bscan<<<NBUK, 512, 0, stream>>>(gh, btot);
    scan_btot<<<1, 1024, 0, stream>>>(btot, bbase);
    bpart<<<NCH, 256, 0, stream>>>(erow, ecol, ew, gh, bbase, stg);
    bucket_sort2<<<NBUK, 256, 0, stream>>>(bbase, stg, cw, rowp);

    // 3) 10 propagation iterations on scaled fp16 state (c = 16)
    const __half* qi = q0;
    for (int it = 1; it < ITERS; ++it) {
        __half* qo = (it & 1) ? qA : qB;
        float beta = (float)(0.1 / pow(16.0, (double)it));
        spmm_kernel<0><<<(N_NODES + 3) / 4, 256, 0, stream>>>(rowp, cw, qi, q0, beta, 1.0f, qo, nullptr);
        qi = qo;
    }
    float beta10 = (float)(0.1 / pow(16.0, 10.0));
    float osc    = (float)pow(16.0, 10.0);
    spmm_kernel<1><<<(N_NODES + 3) / 4, 256, 0, stream>>>(rowp, cw, qi, q0, beta10, osc, nullptr, out);
}